// Round 1
// baseline (1303.009 us; speedup 1.0000x reference)
//
#include <hip/hip_runtime.h>
#include <hip/hip_bf16.h>
#include <stddef.h>

// Problem constants
#define NB   65536   // batch
#define XC   130     // x row stride (IN+1+LAT)
#define LATD 128
#define HIDD 2048
#define JC   1024    // collapsed output cols (IN+1)*OUT
#define OC   512     // OUT

typedef __bf16 bf16_t;
typedef bf16_t bf16x8 __attribute__((ext_vector_type(8)));
typedef float  f32x4  __attribute__((ext_vector_type(4)));

// ---------- prep 1: fc1wT[n][k] = bf16(fc1_w[k][n]), n in [0,2048), k in [0,128)
__global__ void prep_fc1(const float* __restrict__ fc1w, bf16_t* __restrict__ fc1wT) {
  int t = blockIdx.x * blockDim.x + threadIdx.x;     // 262144 threads
  int k = t & (LATD - 1);
  int n = t >> 7;
  fc1wT[(size_t)n * LATD + k] = (bf16_t)fc1w[(size_t)k * HIDD + n];
}

// ---------- prep 2: collapse fc2 against v, permute cols, transpose.
// c in [0,1024): jj = (c>>1) + (c&1)*512  (even c -> weight col, odd c -> bias col)
// W2pT[c][k] = bf16( fc2w[k][2jj]*v0 + fc2w[k][2jj+1]*v1 ),  b2p[c] likewise from fc2b.
__global__ void prep_fc2(const float* __restrict__ x, const float* __restrict__ fc2w,
                         const float* __restrict__ fc2b, const float* __restrict__ dil,
                         const float* __restrict__ shp, bf16_t* __restrict__ w2pT,
                         float* __restrict__ b2p) {
  int t = blockIdx.x * blockDim.x + threadIdx.x;     // 2097152 threads
  int k = t & (HIDD - 1);
  int c = t >> 11;
  float s  = x[(size_t)(NB - 1) * XC + 1];
  float t0 = s * dil[0] + shp[0];
  float t1 = s * dil[1] + shp[1];
  float t2 = s * dil[2] + shp[2];
  float t3 = s * dil[3] + shp[3];
  float v0 = cosf(t0) + cosf(t2);
  float v1 = sinf(t1) + sinf(t3);
  int jj = (c >> 1) + ((c & 1) << 9);
  float w0 = fc2w[(size_t)k * 2048 + 2 * jj];
  float w1 = fc2w[(size_t)k * 2048 + 2 * jj + 1];
  w2pT[(size_t)c * HIDD + k] = (bf16_t)(w0 * v0 + w1 * v1);
  if (k == 0) b2p[c] = fc2b[2 * jj] * v0 + fc2b[2 * jj + 1] * v1;
}

// ---------- main fused kernel
// Block: 32 rows x 1024 cols of Wh = h @ W2pT, h computed on the fly in 32x64 chunks.
// 512 threads = 8 waves. GEMM1: wave w -> h tile (mt=w&1, nt=w>>1).
// GEMM2: wave w -> cols [w*128, w*128+128), rows all 32 (2 mtiles x 8 ntiles = 32 acc f32x4... 16 frags).
__global__ __launch_bounds__(512) void wag_main(
    const float* __restrict__ x, const float* __restrict__ fc1b,
    const bf16_t* __restrict__ fc1wT, const bf16_t* __restrict__ w2pT,
    const float* __restrict__ b2p, float* __restrict__ out)
{
  __shared__ bf16_t z_lds[32 * 128];   // XOR-swizzled, row stride 256B
  __shared__ bf16_t h_lds[32 * 64];    // XOR-swizzled, row stride 128B
  __shared__ float  inp_lds[32];

  const int t   = threadIdx.x;
  const int w   = t >> 6;
  const int l   = t & 63;
  const int lhi = l >> 4;     // 0..3
  const int llo = l & 15;
  const int b0  = blockIdx.x * 32;

  // ---- stage z tile (32x128 bf16) + inp column
  {
    int row = t >> 4, seg = t & 15;
    const float* src = x + (size_t)(b0 + row) * XC + 2 + seg * 8;
    bf16x8 pk;
#pragma unroll
    for (int i = 0; i < 4; ++i) {
      float2 f = *(const float2*)(src + 2 * i);   // 8B-aligned always
      pk[2 * i]     = (bf16_t)f.x;
      pk[2 * i + 1] = (bf16_t)f.y;
    }
    int zb = (row * 256 + seg * 16) ^ ((row & 7) << 4);
    *(bf16x8*)((char*)z_lds + zb) = pk;
    if (t < 32) inp_lds[t] = x[(size_t)(b0 + t) * XC];
  }
  __syncthreads();

  f32x4 acc[2][8] = {};
  const int mt1 = w & 1;
  const int nt1 = w >> 1;

  for (int kc = 0; kc < 32; ++kc) {
    // ---- GEMM1: this wave's 16x16 tile of h chunk (32 x 64), K = 128
    f32x4 acc1 = {};
    const int hn = kc * 64 + nt1 * 16 + llo;   // global hid col (B n-index, bias index)
#pragma unroll
    for (int ks = 0; ks < 4; ++ks) {
      int zr = mt1 * 16 + llo;
      int zb = (zr * 256 + ks * 64 + lhi * 16) ^ ((zr & 7) << 4);
      bf16x8 a = *(const bf16x8*)((const char*)z_lds + zb);
      bf16x8 b = *(const bf16x8*)(fc1wT + (size_t)hn * LATD + ks * 32 + lhi * 8);
      acc1 = __builtin_amdgcn_mfma_f32_16x16x32_bf16(a, b, acc1, 0, 0, 0);
    }
    float bias = fc1b[hn];

    __syncthreads();   // previous iteration's GEMM2 reads of h_lds are done
    // tanh + store h tile (D layout: col=llo, row=lhi*4+r — HW-measured)
#pragma unroll
    for (int r = 0; r < 4; ++r) {
      float pre = acc1[r] + bias;
      float e   = __builtin_amdgcn_exp2f(pre * 2.88539008177792681f);   // e^(2x)
      float th  = 1.0f - 2.0f * __builtin_amdgcn_rcpf(e + 1.0f);
      int hr = mt1 * 16 + lhi * 4 + r;
      int hb = (hr * 128 + (nt1 * 16 + llo) * 2) ^ ((hr & 7) << 4);
      *(bf16_t*)((char*)h_lds + hb) = (bf16_t)th;
    }
    __syncthreads();

    // ---- GEMM2: acc += h_chunk @ W2pT[:, kc*64 .. +64)
#pragma unroll
    for (int ks = 0; ks < 2; ++ks) {
      bf16x8 a[2];
#pragma unroll
      for (int mt = 0; mt < 2; ++mt) {
        int hr = mt * 16 + llo;
        int hb = (hr * 128 + ks * 64 + lhi * 16) ^ ((hr & 7) << 4);
        a[mt] = *(const bf16x8*)((const char*)h_lds + hb);
      }
#pragma unroll
      for (int nt = 0; nt < 8; ++nt) {
        int c = w * 128 + nt * 16 + llo;
        bf16x8 b = *(const bf16x8*)(w2pT + (size_t)c * HIDD + kc * 64 + ks * 32 + lhi * 8);
        acc[0][nt] = __builtin_amdgcn_mfma_f32_16x16x32_bf16(a[0], b, acc[0][nt], 0, 0, 0);
        acc[1][nt] = __builtin_amdgcn_mfma_f32_16x16x32_bf16(a[1], b, acc[1][nt], 0, 0, 0);
      }
    }
  }

  // ---- epilogue: pair adjacent interleaved columns (even=weight, odd=bias)
#pragma unroll
  for (int nt = 0; nt < 8; ++nt) {
    int c = w * 128 + nt * 16 + llo;
    float bb = b2p[c];
#pragma unroll
    for (int mt = 0; mt < 2; ++mt) {
#pragma unroll
      for (int r = 0; r < 4; ++r) {
        float comb    = acc[mt][nt][r] + bb;
        float partner = __shfl_xor(comb, 1, 64);
        if ((l & 1) == 0) {
          int row = mt * 16 + lhi * 4 + r;
          out[(size_t)(b0 + row) * OC + (c >> 1)] = inp_lds[row] * comb + partner;
        }
      }
    }
  }
}

extern "C" void kernel_launch(void* const* d_in, const int* in_sizes, int n_in,
                              void* d_out, int out_size, void* d_ws, size_t ws_size,
                              hipStream_t stream) {
  const float* x    = (const float*)d_in[0];
  const float* fc1w = (const float*)d_in[1];
  const float* fc1b = (const float*)d_in[2];
  const float* fc2w = (const float*)d_in[3];
  const float* fc2b = (const float*)d_in[4];
  const float* dil  = (const float*)d_in[5];
  const float* shp  = (const float*)d_in[6];
  float* out = (float*)d_out;

  // ws layout: fc1wT (512KB bf16) | w2pT (4MB bf16) | b2p (4KB f32)  => ~4.7MB
  bf16_t* fc1wT = (bf16_t*)d_ws;
  bf16_t* w2pT  = fc1wT + (size_t)HIDD * LATD;
  float*  b2p   = (float*)(w2pT + (size_t)JC * HIDD);

  prep_fc1<<<(HIDD * LATD) / 256, 256, 0, stream>>>(fc1w, fc1wT);
  prep_fc2<<<(JC * HIDD) / 256, 256, 0, stream>>>(x, fc2w, fc2b, dil, shp, w2pT, b2p);
  wag_main<<<NB / 32, 512, 0, stream>>>(x, fc1b, fc1wT, w2pT, b2p, out);
}

// Round 2
// 1015.756 us; speedup vs baseline: 1.2828x; 1.2828x over previous
//
#include <hip/hip_runtime.h>
#include <hip/hip_bf16.h>
#include <stddef.h>

// Problem constants
#define NB   65536   // batch
#define XC   130     // x row stride (IN+1+LAT)
#define LATD 128
#define HIDD 2048
#define JC   1024    // collapsed output cols (IN+1)*OUT
#define OC   512     // OUT
#define BM   128     // rows per block
#define BN   512     // cols per block (2 col-blocks)

typedef __bf16 bf16_t;
typedef bf16_t bf16x8 __attribute__((ext_vector_type(8)));
typedef float  f32x4  __attribute__((ext_vector_type(4)));

// ---------- prep 1: fc1wT[n][k] = bf16(fc1_w[k][n])
__global__ void prep_fc1(const float* __restrict__ fc1w, bf16_t* __restrict__ fc1wT) {
  int t = blockIdx.x * blockDim.x + threadIdx.x;
  int k = t & (LATD - 1);
  int n = t >> 7;
  fc1wT[(size_t)n * LATD + k] = (bf16_t)fc1w[(size_t)k * HIDD + n];
}

// ---------- prep 2: collapse fc2 against v, permute cols (even=weight, odd=bias), transpose
__global__ void prep_fc2(const float* __restrict__ x, const float* __restrict__ fc2w,
                         const float* __restrict__ fc2b, const float* __restrict__ dil,
                         const float* __restrict__ shp, bf16_t* __restrict__ w2pT,
                         float* __restrict__ b2p) {
  int t = blockIdx.x * blockDim.x + threadIdx.x;
  int k = t & (HIDD - 1);
  int c = t >> 11;
  float s  = x[(size_t)(NB - 1) * XC + 1];
  float t0 = s * dil[0] + shp[0];
  float t1 = s * dil[1] + shp[1];
  float t2 = s * dil[2] + shp[2];
  float t3 = s * dil[3] + shp[3];
  float v0 = cosf(t0) + cosf(t2);
  float v1 = sinf(t1) + sinf(t3);
  int jj = (c >> 1) + ((c & 1) << 9);
  float w0 = fc2w[(size_t)k * 2048 + 2 * jj];
  float w1 = fc2w[(size_t)k * 2048 + 2 * jj + 1];
  w2pT[(size_t)c * HIDD + k] = (bf16_t)(w0 * v0 + w1 * v1);
  if (k == 0) b2p[c] = fc2b[2 * jj] * v0 + fc2b[2 * jj + 1] * v1;
}

// ---------- main fused kernel
// Block: BM=128 rows x BN=512 cols. 8 waves. Per K-chunk (64 hid cols):
//   G1: wave w computes h rows [w*16,+16) x 64 cols -> h_lds[buf^1]   (16 MFMA)
//   G2: wave w accumulates 128 rows x cols [w*64,+64) from h_lds[buf] (64 MFMA)
// Single barrier per chunk; h double-buffered so G1(kc+1) overlaps G2(kc).
__global__ __launch_bounds__(512, 2) void wag_main(
    const float* __restrict__ x, const float* __restrict__ fc1b,
    const bf16_t* __restrict__ fc1wT, const bf16_t* __restrict__ w2pT,
    const float* __restrict__ b2p, float* __restrict__ out)
{
  __shared__ bf16_t z_lds[BM * LATD];     // 32KB, row stride 256B, XOR-swizzled
  __shared__ bf16_t h_lds[2][BM * 64];    // 2x16KB, row stride 128B, XOR-swizzled
  __shared__ float  inp_lds[BM];

  const int t   = threadIdx.x;
  const int w   = t >> 6;
  const int l   = t & 63;
  const int lhi = l >> 4;
  const int llo = l & 15;
  const size_t b0 = (size_t)blockIdx.x * BM;
  const int    bc = blockIdx.y * BN;

  // ---- stage z tile (128x128 bf16) + inp column
  {
    int row  = t >> 2;
    int segb = (t & 3) * 64;                       // byte offset of this 32-col segment
    const float* src = x + (size_t)(b0 + row) * XC + 2 + (t & 3) * 32;
#pragma unroll
    for (int j = 0; j < 4; ++j) {
      bf16x8 pk;
#pragma unroll
      for (int i = 0; i < 4; ++i) {
        float2 f = *(const float2*)(src + j * 8 + 2 * i);   // 8B-aligned
        pk[2 * i]     = (bf16_t)f.x;
        pk[2 * i + 1] = (bf16_t)f.y;
      }
      int zb = (row * 256 + segb + j * 16) ^ ((row & 7) << 4);
      *(bf16x8*)((char*)z_lds + zb) = pk;
    }
    if (t < BM) inp_lds[t] = x[(size_t)(b0 + t) * XC];
  }
  __syncthreads();

  f32x4 acc[8][4] = {};

  auto G1 = [&](int kc, int buf) {
    const int zr = w * 16 + llo;
    bf16x8 a[4];
#pragma unroll
    for (int ks = 0; ks < 4; ++ks)
      a[ks] = *(const bf16x8*)((const char*)z_lds +
               ((zr * 256 + ks * 64 + lhi * 16) ^ ((zr & 7) << 4)));
#pragma unroll
    for (int nt = 0; nt < 4; ++nt) {
      int hn = kc * 64 + nt * 16 + llo;           // global hid col
      f32x4 c1 = {};
#pragma unroll
      for (int ks = 0; ks < 4; ++ks) {
        bf16x8 b = *(const bf16x8*)(fc1wT + (size_t)hn * LATD + ks * 32 + lhi * 8);
        c1 = __builtin_amdgcn_mfma_f32_16x16x32_bf16(a[ks], b, c1, 0, 0, 0);
      }
      float bias = fc1b[hn];
#pragma unroll
      for (int r = 0; r < 4; ++r) {
        float pre = c1[r] + bias;
        float e   = __builtin_amdgcn_exp2f(pre * 2.88539008177792681f);  // e^(2x)
        float th  = 1.0f - 2.0f * __builtin_amdgcn_rcpf(e + 1.0f);
        int hr = w * 16 + lhi * 4 + r;
        int hb = (hr * 128 + (nt * 16 + llo) * 2) ^ ((hr & 7) << 4);
        *(bf16_t*)((char*)h_lds[buf] + hb) = (bf16_t)th;
      }
    }
  };

  auto G2 = [&](int kc, int buf) {
#pragma unroll
    for (int ks = 0; ks < 2; ++ks) {
      bf16x8 a[8];
#pragma unroll
      for (int mt = 0; mt < 8; ++mt) {
        int hr = mt * 16 + llo;
        a[mt] = *(const bf16x8*)((const char*)h_lds[buf] +
                 ((hr * 128 + ks * 64 + lhi * 16) ^ ((hr & 7) << 4)));
      }
#pragma unroll
      for (int nt = 0; nt < 4; ++nt) {
        int c = bc + w * 64 + nt * 16 + llo;
        bf16x8 b = *(const bf16x8*)(w2pT + (size_t)c * HIDD + kc * 64 + ks * 32 + lhi * 8);
#pragma unroll
        for (int mt = 0; mt < 8; ++mt)
          acc[mt][nt] = __builtin_amdgcn_mfma_f32_16x16x32_bf16(a[mt], b, acc[mt][nt], 0, 0, 0);
      }
    }
  };

  G1(0, 0);
  __syncthreads();
  for (int kc = 0; kc < 32; ++kc) {
    if (kc < 31) G1(kc + 1, (kc + 1) & 1);
    G2(kc, kc & 1);
    __syncthreads();
  }

  // ---- epilogue: pair adjacent interleaved columns (even=weight, odd=bias)
#pragma unroll
  for (int nt = 0; nt < 4; ++nt) {
    int c = bc + w * 64 + nt * 16 + llo;
    float bb = b2p[c];
#pragma unroll
    for (int mt = 0; mt < 8; ++mt) {
#pragma unroll
      for (int r = 0; r < 4; ++r) {
        float comb    = acc[mt][nt][r] + bb;
        float partner = __shfl_xor(comb, 1, 64);
        if ((l & 1) == 0) {
          int row = mt * 16 + lhi * 4 + r;
          out[(b0 + row) * OC + (c >> 1)] = inp_lds[row] * comb + partner;
        }
      }
    }
  }
}

extern "C" void kernel_launch(void* const* d_in, const int* in_sizes, int n_in,
                              void* d_out, int out_size, void* d_ws, size_t ws_size,
                              hipStream_t stream) {
  const float* x    = (const float*)d_in[0];
  const float* fc1w = (const float*)d_in[1];
  const float* fc1b = (const float*)d_in[2];
  const float* fc2w = (const float*)d_in[3];
  const float* fc2b = (const float*)d_in[4];
  const float* dil  = (const float*)d_in[5];
  const float* shp  = (const float*)d_in[6];
  float* out = (float*)d_out;

  // ws layout: fc1wT (512KB bf16) | w2pT (4MB bf16) | b2p (4KB f32)
  bf16_t* fc1wT = (bf16_t*)d_ws;
  bf16_t* w2pT  = fc1wT + (size_t)HIDD * LATD;
  float*  b2p   = (float*)(w2pT + (size_t)JC * HIDD);

  prep_fc1<<<(HIDD * LATD) / 256, 256, 0, stream>>>(fc1w, fc1wT);
  prep_fc2<<<(JC * HIDD) / 256, 256, 0, stream>>>(x, fc2w, fc2b, dil, shp, w2pT, b2p);
  wag_main<<<dim3(NB / BM, JC / BN), 512, 0, stream>>>(x, fc1b, fc1wT, w2pT, b2p, out);
}

// Round 3
// 943.398 us; speedup vs baseline: 1.3812x; 1.0767x over previous
//
#include <hip/hip_runtime.h>
#include <hip/hip_bf16.h>
#include <stddef.h>

// Problem constants
#define NB   65536   // batch
#define XC   130     // x row stride (IN+1+LAT)
#define LATD 128
#define HIDD 2048
#define JC   1024    // collapsed output cols (IN+1)*OUT
#define OC   512     // OUT
#define BM   128     // rows per block
#define BN   512     // cols per block

typedef __bf16 bf16_t;
typedef bf16_t bf16x8 __attribute__((ext_vector_type(8)));
typedef float  f32x4  __attribute__((ext_vector_type(4)));

// ---------- prep 1: fc1wT[n][k] = bf16(fc1_w[k][n])
__global__ void prep_fc1(const float* __restrict__ fc1w, bf16_t* __restrict__ fc1wT) {
  int t = blockIdx.x * blockDim.x + threadIdx.x;
  int k = t & (LATD - 1);
  int n = t >> 7;
  fc1wT[(size_t)n * LATD + k] = (bf16_t)fc1w[(size_t)k * HIDD + n];
}

// ---------- prep 2: collapse fc2 against v, permute cols (even=weight, odd=bias), transpose
__global__ void prep_fc2(const float* __restrict__ x, const float* __restrict__ fc2w,
                         const float* __restrict__ fc2b, const float* __restrict__ dil,
                         const float* __restrict__ shp, bf16_t* __restrict__ w2pT,
                         float* __restrict__ b2p) {
  int t = blockIdx.x * blockDim.x + threadIdx.x;
  int k = t & (HIDD - 1);
  int c = t >> 11;
  float s  = x[(size_t)(NB - 1) * XC + 1];
  float t0 = s * dil[0] + shp[0];
  float t1 = s * dil[1] + shp[1];
  float t2 = s * dil[2] + shp[2];
  float t3 = s * dil[3] + shp[3];
  float v0 = cosf(t0) + cosf(t2);
  float v1 = sinf(t1) + sinf(t3);
  int jj = (c >> 1) + ((c & 1) << 9);
  float w0 = fc2w[(size_t)k * 2048 + 2 * jj];
  float w1 = fc2w[(size_t)k * 2048 + 2 * jj + 1];
  w2pT[(size_t)c * HIDD + k] = (bf16_t)(w0 * v0 + w1 * v1);
  if (k == 0) b2p[c] = fc2b[2 * jj] * v0 + fc2b[2 * jj + 1] * v1;
}

// ---------- main fused kernel
// 1024 threads = 16 waves. Block: BM=128 rows x BN=512 cols.
// Per K-chunk kc (64 hid cols):
//   G1: wave w computes h rows (w&7)*16..+16, col-half (w>>3)*32..+32  (8 MFMA)
//       A-operand (z) lives in registers (16 VGPR/lane), loaded once per block.
//   G2: wave w accumulates 128 rows x cols [w*32,+32) from h_lds[buf]  (32 MFMA)
// Single barrier per chunk; h double-buffered so G1(kc+1) overlaps G2(kc).
__global__ __launch_bounds__(1024, 4) void wag_main(
    const float* __restrict__ x, const float* __restrict__ fc1b,
    const bf16_t* __restrict__ fc1wT, const bf16_t* __restrict__ w2pT,
    const float* __restrict__ b2p, float* __restrict__ out)
{
  __shared__ bf16_t h_lds[2][BM * 64];    // 2x16KB, row stride 128B, XOR-swizzled
  __shared__ float  inp_lds[BM];

  const int t   = threadIdx.x;
  const int w   = t >> 6;
  const int l   = t & 63;
  const int lhi = l >> 4;
  const int llo = l & 15;
  const size_t b0 = (size_t)blockIdx.x * BM;
  const int    bc = blockIdx.y * BN;
  const int    g1r = (w & 7) * 16;        // G1 row-group base
  const int    g1c = (w >> 3) * 32;       // G1 col-half base within 64-chunk

  // ---- load this lane's z row into registers (z[g1r+llo][0..128) -> 4x bf16x8)
  bf16x8 za[4];
  {
    const float* zsrc = x + (b0 + g1r + llo) * XC + 2;
#pragma unroll
    for (int ks = 0; ks < 4; ++ks) {
      bf16x8 pk;
#pragma unroll
      for (int i = 0; i < 4; ++i) {
        float2 f = *(const float2*)(zsrc + ks * 32 + lhi * 8 + 2 * i);  // 8B-aligned
        pk[2 * i]     = (bf16_t)f.x;
        pk[2 * i + 1] = (bf16_t)f.y;
      }
      za[ks] = pk;
    }
    if (t < BM) inp_lds[t] = x[(b0 + t) * XC];
  }

  f32x4 acc[8][2] = {};

  auto G1 = [&](int kc, int buf) {
#pragma unroll
    for (int nt = 0; nt < 2; ++nt) {
      int hn = kc * 64 + g1c + nt * 16 + llo;      // global hid col
      f32x4 c1 = {};
#pragma unroll
      for (int ks = 0; ks < 4; ++ks) {
        bf16x8 b = *(const bf16x8*)(fc1wT + (size_t)hn * LATD + ks * 32 + lhi * 8);
        c1 = __builtin_amdgcn_mfma_f32_16x16x32_bf16(za[ks], b, c1, 0, 0, 0);
      }
      float bias = fc1b[hn];
#pragma unroll
      for (int r = 0; r < 4; ++r) {
        float pre = c1[r] + bias;
        float e   = __builtin_amdgcn_exp2f(pre * 2.88539008177792681f);  // e^(2x)
        float th  = 1.0f - 2.0f * __builtin_amdgcn_rcpf(e + 1.0f);
        int hr = g1r + lhi * 4 + r;
        int hb = (hr * 128 + (g1c + nt * 16 + llo) * 2) ^ ((hr & 7) << 4);
        *(bf16_t*)((char*)h_lds[buf] + hb) = (bf16_t)th;
      }
    }
  };

  auto G2 = [&](int kc, int buf) {
#pragma unroll
    for (int ks = 0; ks < 2; ++ks) {
      int c0 = bc + w * 32 + llo;
      bf16x8 b0r = *(const bf16x8*)(w2pT + (size_t)c0 * HIDD + kc * 64 + ks * 32 + lhi * 8);
      bf16x8 b1r = *(const bf16x8*)(w2pT + (size_t)(c0 + 16) * HIDD + kc * 64 + ks * 32 + lhi * 8);
#pragma unroll
      for (int mt = 0; mt < 8; ++mt) {
        int hr = mt * 16 + llo;
        bf16x8 a = *(const bf16x8*)((const char*)h_lds[buf] +
                   ((hr * 128 + ks * 64 + lhi * 16) ^ ((hr & 7) << 4)));
        acc[mt][0] = __builtin_amdgcn_mfma_f32_16x16x32_bf16(a, b0r, acc[mt][0], 0, 0, 0);
        acc[mt][1] = __builtin_amdgcn_mfma_f32_16x16x32_bf16(a, b1r, acc[mt][1], 0, 0, 0);
      }
    }
  };

  G1(0, 0);
  __syncthreads();
  for (int kc = 0; kc < 32; ++kc) {
    if (kc < 31) G1(kc + 1, (kc + 1) & 1);
    G2(kc, kc & 1);
    __syncthreads();
  }

  // ---- epilogue: pair adjacent interleaved columns (even=weight, odd=bias)
#pragma unroll
  for (int nt = 0; nt < 2; ++nt) {
    int c = bc + w * 32 + nt * 16 + llo;
    float bb = b2p[c];
#pragma unroll
    for (int mt = 0; mt < 8; ++mt) {
#pragma unroll
      for (int r = 0; r < 4; ++r) {
        float comb    = acc[mt][nt][r] + bb;
        float partner = __shfl_xor(comb, 1, 64);
        if ((l & 1) == 0) {
          int row = mt * 16 + lhi * 4 + r;
          out[(b0 + row) * OC + (c >> 1)] = inp_lds[row] * comb + partner;
        }
      }
    }
  }
}

extern "C" void kernel_launch(void* const* d_in, const int* in_sizes, int n_in,
                              void* d_out, int out_size, void* d_ws, size_t ws_size,
                              hipStream_t stream) {
  const float* x    = (const float*)d_in[0];
  const float* fc1w = (const float*)d_in[1];
  const float* fc1b = (const float*)d_in[2];
  const float* fc2w = (const float*)d_in[3];
  const float* fc2b = (const float*)d_in[4];
  const float* dil  = (const float*)d_in[5];
  const float* shp  = (const float*)d_in[6];
  float* out = (float*)d_out;

  // ws layout: fc1wT (512KB bf16) | w2pT (4MB bf16) | b2p (4KB f32)
  bf16_t* fc1wT = (bf16_t*)d_ws;
  bf16_t* w2pT  = fc1wT + (size_t)HIDD * LATD;
  float*  b2p   = (float*)(w2pT + (size_t)JC * HIDD);

  prep_fc1<<<(HIDD * LATD) / 256, 256, 0, stream>>>(fc1w, fc1wT);
  prep_fc2<<<(JC * HIDD) / 256, 256, 0, stream>>>(x, fc2w, fc2b, dil, shp, w2pT, b2p);
  wag_main<<<dim3(NB / BM, JC / BN), 1024, 0, stream>>>(x, fc1b, fc1wT, w2pT, b2p, out);
}

// Round 4
// 513.986 us; speedup vs baseline: 2.5351x; 1.8355x over previous
//
#include <hip/hip_runtime.h>
#include <hip/hip_bf16.h>
#include <stddef.h>

// Problem constants
#define NB   65536   // batch
#define XC   130     // x row stride (IN+1+LAT)
#define LATD 128
#define HIDD 2048
#define JC   1024    // collapsed output cols (IN+1)*OUT
#define OC   512     // OUT
#define BM   128     // rows per block
#define BN   512     // collapsed cols per block

typedef __bf16 bf16_t;
typedef bf16_t bf16x8 __attribute__((ext_vector_type(8)));
typedef float  f32x4  __attribute__((ext_vector_type(4)));

typedef __attribute__((address_space(1))) const unsigned char ga_u8;
typedef __attribute__((address_space(3))) unsigned char ls_u8;

__device__ __forceinline__ void dma16(const void* g, void* l) {
  __builtin_amdgcn_global_load_lds((ga_u8*)g, (ls_u8*)l, 16, 0, 0);
}

// ---------- prep 1: fc1wT[n][k] = bf16(fc1_w[k][n])
__global__ void prep_fc1(const float* __restrict__ fc1w, bf16_t* __restrict__ fc1wT) {
  int t = blockIdx.x * blockDim.x + threadIdx.x;
  int k = t & (LATD - 1);
  int n = t >> 7;
  fc1wT[(size_t)n * LATD + k] = (bf16_t)fc1w[(size_t)k * HIDD + n];
}

// ---------- prep 2: collapse fc2 against v, permute cols, transpose.
// Permutation: collapsed c -> group g=c>>5, half=(c>>4)&1, col16=c&15.
// out-col o = g*16+col16; jj = o + half*512 (half 0=weight, 1=bias).
// So cols [g*32, g*32+16) = weights of out-cols [g*16,+16); [+16,+32) = their biases.
__global__ void prep_fc2(const float* __restrict__ x, const float* __restrict__ fc2w,
                         const float* __restrict__ fc2b, const float* __restrict__ dil,
                         const float* __restrict__ shp, bf16_t* __restrict__ w2pT,
                         float* __restrict__ b2p) {
  int t = blockIdx.x * blockDim.x + threadIdx.x;
  int k = t & (HIDD - 1);
  int c = t >> 11;
  float s  = x[(size_t)(NB - 1) * XC + 1];
  float t0 = s * dil[0] + shp[0];
  float t1 = s * dil[1] + shp[1];
  float t2 = s * dil[2] + shp[2];
  float t3 = s * dil[3] + shp[3];
  float v0 = cosf(t0) + cosf(t2);
  float v1 = sinf(t1) + sinf(t3);
  int jj = ((c >> 5) * 16 + (c & 15)) + (((c >> 4) & 1) << 9);
  float w0 = fc2w[(size_t)k * 2048 + 2 * jj];
  float w1 = fc2w[(size_t)k * 2048 + 2 * jj + 1];
  w2pT[(size_t)c * HIDD + k] = (bf16_t)(w0 * v0 + w1 * v1);
  if (k == 0) b2p[c] = fc2b[2 * jj] * v0 + fc2b[2 * jj + 1] * v1;
}

// ---------- main fused kernel: 512 threads = 8 waves, BM=128 x BN=512.
// Per K-chunk (64 hid cols), 2 barriers:
//   G2(kc) [reads w2t + h[kc&1]] ; bar ; DMA(w2t kc+1, f1t kc+2) + G1(kc+1) ; bar
// All B-operands staged via global_load_lds (pre-swizzled src, XOR-swizzled reads).
__global__ __launch_bounds__(512, 2) void wag_main(
    const float* __restrict__ x, const float* __restrict__ fc1b,
    const bf16_t* __restrict__ fc1wT, const bf16_t* __restrict__ w2pT,
    const float* __restrict__ b2p, float* __restrict__ out)
{
  __shared__ bf16_t w2t[BN * 64];        // 64KB: [col][k], 128B rows, swizzled
  __shared__ bf16_t f1t[2][64 * LATD];   // 2x16KB: [col][k], 256B rows, swizzled
  __shared__ bf16_t h_lds[2][BM * 64];   // 2x16KB: [row][col], 128B rows, swizzled
  __shared__ float  inp_lds[BM];

  const int t   = threadIdx.x;
  const int w   = t >> 6;     // 0..7
  const int l   = t & 63;
  const int lhi = l >> 4;
  const int llo = l & 15;
  const size_t b0 = (size_t)blockIdx.x * BM;
  const int    bc = blockIdx.y * BN;

  // ---- z row for this lane (G1 A-operand, rows w*16+llo), in registers
  bf16x8 za[4];
  {
    const float* zsrc = x + (b0 + w * 16 + llo) * XC + 2;
#pragma unroll
    for (int ks = 0; ks < 4; ++ks) {
      bf16x8 pk;
#pragma unroll
      for (int i = 0; i < 4; ++i) {
        float2 f = *(const float2*)(zsrc + ks * 32 + lhi * 8 + 2 * i);
        pk[2 * i]     = (bf16_t)f.x;
        pk[2 * i + 1] = (bf16_t)f.y;
      }
      za[ks] = pk;
    }
    if (t < BM) inp_lds[t] = x[(b0 + t) * XC];
  }

  f32x4 acc[4][8] = {};

  // ---- DMA stagers (dest linear = wave-uniform base + lane*16; src pre-swizzled)
  auto stage_w2 = [&](int kc) {          // 512 cols x 64 k = 64KB, 64 instrs
#pragma unroll
    for (int q = 0; q < 8; ++q) {
      int j   = w * 8 + q;
      int col = j * 8 + (l >> 3);
      int kb  = ((l & 7) * 16) ^ ((col & 7) << 4);
      const char* src = (const char*)w2pT + ((size_t)(bc + col) * HIDD + kc * 64) * 2 + kb;
      dma16(src, (char*)w2t + j * 1024);
    }
  };
  auto stage_f1 = [&](int j64, int buf) { // hid cols j64*64..+64, 16KB, 16 instrs
#pragma unroll
    for (int q = 0; q < 2; ++q) {
      int j   = w * 2 + q;
      int col = j * 4 + (l >> 4);
      int kb  = ((l & 15) * 16) ^ ((col & 7) << 4);
      const char* src = (const char*)fc1wT + ((size_t)(j64 * 64 + col) * LATD) * 2 + kb;
      dma16(src, (char*)f1t[buf] + j * 1024);
    }
  };

  // ---- G1: h rows w*16..+16, cols 0..63 of chunk j (reads f1t[j&1], writes h[j&1])
  auto G1 = [&](int j) {
    const int buf = j & 1;
#pragma unroll
    for (int nt = 0; nt < 4; ++nt) {
      int col = nt * 16 + llo;
      f32x4 c1 = {};
#pragma unroll
      for (int ks = 0; ks < 4; ++ks) {
        int fb = col * 256 + ((ks * 64 + lhi * 16) ^ ((col & 7) << 4));
        bf16x8 b = *(const bf16x8*)((const char*)f1t[buf] + fb);
        c1 = __builtin_amdgcn_mfma_f32_16x16x32_bf16(za[ks], b, c1, 0, 0, 0);
      }
      float bias = fc1b[j * 64 + col];
#pragma unroll
      for (int r = 0; r < 4; ++r) {
        float pre = c1[r] + bias;
        float e   = __builtin_amdgcn_exp2f(pre * 2.88539008177792681f);  // e^(2x)
        float th  = 1.0f - 2.0f * __builtin_amdgcn_rcpf(e + 1.0f);
        int hr = w * 16 + lhi * 4 + r;
        int hb = (hr * 128 + col * 2) ^ ((hr & 7) << 4);
        *(bf16_t*)((char*)h_lds[buf] + hb) = (bf16_t)th;
      }
    }
  };

  // ---- G2: wave tile 64 rows x 128 cols; reads h[kc&1] + w2t
  auto G2 = [&](int kc) {
    const int hbuf = kc & 1;
    const int mrb  = (w & 1) * 64;
    const int ncb  = (w >> 1) * 128;
#pragma unroll
    for (int ks = 0; ks < 2; ++ks) {
      bf16x8 a[4];
#pragma unroll
      for (int mt = 0; mt < 4; ++mt) {
        int hr = mrb + mt * 16 + llo;
        a[mt] = *(const bf16x8*)((const char*)h_lds[hbuf] +
                 ((hr * 128 + ks * 64 + lhi * 16) ^ ((hr & 7) << 4)));
      }
#pragma unroll
      for (int nt = 0; nt < 8; ++nt) {
        int col = ncb + nt * 16 + llo;
        int wb  = col * 128 + ((ks * 64 + lhi * 16) ^ ((col & 7) << 4));
        bf16x8 b = *(const bf16x8*)((const char*)w2t + wb);
#pragma unroll
        for (int mt = 0; mt < 4; ++mt)
          acc[mt][nt] = __builtin_amdgcn_mfma_f32_16x16x32_bf16(a[mt], b, acc[mt][nt], 0, 0, 0);
      }
    }
  };

  // ---- pipeline
  stage_f1(0, 0);
  stage_w2(0);
  __syncthreads();             // f1t[0], w2t(0) complete (vmcnt drained)
  stage_f1(1, 1);
  G1(0);
  __syncthreads();             // h[0] ready, f1t[1] complete

  for (int kc = 0; kc < 31; ++kc) {
    G2(kc);
    __syncthreads();           // everyone done reading w2t
    stage_w2(kc + 1);
    if (kc < 30) stage_f1(kc + 2, kc & 1);
    G1(kc + 1);
    __syncthreads();           // DMA drained, h[(kc+1)&1] ready
  }
  G2(31);

  // ---- epilogue: weight (nt even) and bias (nt odd) live in the SAME lane.
  // out col = (bc + ncb + p*32)/2 + llo ; rows: 16 consecutive lanes -> 64B stores.
  {
    const int mrb = (w & 1) * 64;
    const int ncb = (w >> 1) * 128;
#pragma unroll
    for (int p = 0; p < 4; ++p) {
      int cw = bc + ncb + p * 32 + llo;          // collapsed weight col
      float bw = b2p[cw];
      float bb = b2p[cw + 16];
      int oc = (bc + ncb + p * 32) / 2 + llo;    // output col
#pragma unroll
      for (int mt = 0; mt < 4; ++mt) {
#pragma unroll
        for (int r = 0; r < 4; ++r) {
          int row = mrb + mt * 16 + lhi * 4 + r;
          float wv = acc[mt][2 * p][r] + bw;
          float bv = acc[mt][2 * p + 1][r] + bb;
          out[(b0 + row) * OC + oc] = inp_lds[row] * wv + bv;
        }
      }
    }
  }
}

extern "C" void kernel_launch(void* const* d_in, const int* in_sizes, int n_in,
                              void* d_out, int out_size, void* d_ws, size_t ws_size,
                              hipStream_t stream) {
  const float* x    = (const float*)d_in[0];
  const float* fc1w = (const float*)d_in[1];
  const float* fc1b = (const float*)d_in[2];
  const float* fc2w = (const float*)d_in[3];
  const float* fc2b = (const float*)d_in[4];
  const float* dil  = (const float*)d_in[5];
  const float* shp  = (const float*)d_in[6];
  float* out = (float*)d_out;

  // ws layout: fc1wT (512KB bf16) | w2pT (4MB bf16) | b2p (4KB f32)
  bf16_t* fc1wT = (bf16_t*)d_ws;
  bf16_t* w2pT  = fc1wT + (size_t)HIDD * LATD;
  float*  b2p   = (float*)(w2pT + (size_t)JC * HIDD);

  prep_fc1<<<(HIDD * LATD) / 256, 256, 0, stream>>>(fc1w, fc1wT);
  prep_fc2<<<(JC * HIDD) / 256, 256, 0, stream>>>(x, fc2w, fc2b, dil, shp, w2pT, b2p);
  wag_main<<<dim3(NB / BM, JC / BN), 512, 0, stream>>>(x, fc1b, fc1wT, w2pT, b2p, out);
}

// Round 5
// 498.420 us; speedup vs baseline: 2.6143x; 1.0312x over previous
//
#include <hip/hip_runtime.h>
#include <hip/hip_bf16.h>
#include <stddef.h>

// Problem constants
#define NB   65536   // batch
#define XC   130     // x row stride (IN+1+LAT)
#define LATD 128
#define HIDD 2048
#define JC   1024    // collapsed output cols (IN+1)*OUT
#define OC   512     // OUT
#define BM   128     // rows per block
#define BN   512     // collapsed cols per block
#define KCH  32      // K-chunk (hid cols per step)
#define NKC  64      // number of K-chunks (HIDD/KCH)

typedef __bf16 bf16_t;
typedef bf16_t bf16x8 __attribute__((ext_vector_type(8)));
typedef float  f32x4  __attribute__((ext_vector_type(4)));

typedef __attribute__((address_space(1))) const unsigned char ga_u8;
typedef __attribute__((address_space(3))) unsigned char ls_u8;

__device__ __forceinline__ void dma16(const void* g, void* l) {
  __builtin_amdgcn_global_load_lds((ga_u8*)g, (ls_u8*)l, 16, 0, 0);
}

// ---------- prep 1: fc1wT[n][k] = bf16(fc1_w[k][n])
__global__ void prep_fc1(const float* __restrict__ fc1w, bf16_t* __restrict__ fc1wT) {
  int t = blockIdx.x * blockDim.x + threadIdx.x;
  int k = t & (LATD - 1);
  int n = t >> 7;
  fc1wT[(size_t)n * LATD + k] = (bf16_t)fc1w[(size_t)k * HIDD + n];
}

// ---------- prep 2: collapse fc2 against v, permute cols, transpose.
// collapsed c -> g=c>>5, half=(c>>4)&1, col16=c&15; out-col o=g*16+col16; jj=o+half*512.
__global__ void prep_fc2(const float* __restrict__ x, const float* __restrict__ fc2w,
                         const float* __restrict__ fc2b, const float* __restrict__ dil,
                         const float* __restrict__ shp, bf16_t* __restrict__ w2pT,
                         float* __restrict__ b2p) {
  int t = blockIdx.x * blockDim.x + threadIdx.x;
  int k = t & (HIDD - 1);
  int c = t >> 11;
  float s  = x[(size_t)(NB - 1) * XC + 1];
  float t0 = s * dil[0] + shp[0];
  float t1 = s * dil[1] + shp[1];
  float t2 = s * dil[2] + shp[2];
  float t3 = s * dil[3] + shp[3];
  float v0 = cosf(t0) + cosf(t2);
  float v1 = sinf(t1) + sinf(t3);
  int jj = ((c >> 5) * 16 + (c & 15)) + (((c >> 4) & 1) << 9);
  float w0 = fc2w[(size_t)k * 2048 + 2 * jj];
  float w1 = fc2w[(size_t)k * 2048 + 2 * jj + 1];
  w2pT[(size_t)c * HIDD + k] = (bf16_t)(w0 * v0 + w1 * v1);
  if (k == 0) b2p[c] = fc2b[2 * jj] * v0 + fc2b[2 * jj + 1] * v1;
}

// ---------- main fused kernel: 512 threads = 8 waves, BM=128 x BN=512, KCH=32.
// Per chunk kc, ONE barrier:
//   { DMA w2t(kc+1), f1t(kc+2); G1(kc+1); G2(kc); barrier }
// DMAs issue first -> covered by ~1550cy of MFMA; barrier's vmcnt(0) drain is free.
// WAR safety (single barrier): w2t[(kc+1)&1] last read by G2(kc-1) pre-barrier;
// f1t[kc&1] last read by G1(kc) pre-barrier; h col-half (kc+1)&1 last read by
// G2(kc-1) pre-barrier. RAW: barrier drains vmcnt + lgkmcnt.
__global__ __launch_bounds__(512, 2) void wag_main(
    const float* __restrict__ x, const float* __restrict__ fc1b,
    const bf16_t* __restrict__ fc1wT, const bf16_t* __restrict__ w2pT,
    const float* __restrict__ b2p, float* __restrict__ out)
{
  __shared__ bf16_t w2t[2][BN * KCH];    // 2x32KB: [col][k], 64B rows, LINEAR
  __shared__ bf16_t f1t[2][KCH * LATD];  // 2x8KB:  [col][k], 256B rows, XOR-swizzled
  __shared__ bf16_t h_lds[BM * 64];      // 16KB: [row][64 cols], 128B rows, XOR-swizzled
                                         //   col-half parity = chunk parity (built-in dbuf)
  __shared__ float  inp_lds[BM];

  const int t   = threadIdx.x;
  const int w   = t >> 6;     // 0..7
  const int l   = t & 63;
  const int lhi = l >> 4;
  const int llo = l & 15;
  const size_t b0 = (size_t)blockIdx.x * BM;
  const int    bc = blockIdx.y * BN;

  // ---- z row for this lane (G1 A-operand, row w*16+llo, K=128) in registers
  bf16x8 za[4];
  {
    const float* zsrc = x + (b0 + w * 16 + llo) * XC + 2;
#pragma unroll
    for (int ks = 0; ks < 4; ++ks) {
      bf16x8 pk;
#pragma unroll
      for (int i = 0; i < 4; ++i) {
        float2 f = *(const float2*)(zsrc + ks * 32 + lhi * 8 + 2 * i);
        pk[2 * i]     = (bf16_t)f.x;
        pk[2 * i + 1] = (bf16_t)f.y;
      }
      za[ks] = pk;
    }
    if (t < BM) inp_lds[t] = x[(b0 + t) * XC];
  }

  f32x4 acc[4][8] = {};

  // ---- DMA stagers. w2t dest is linear: byte(col,k) = col*64 + k*2 = j*1024 + l*16.
  auto stage_w2 = [&](int kc) {          // 32KB, 4 instr/wave
    const int buf = kc & 1;
#pragma unroll
    for (int q = 0; q < 4; ++q) {
      int j   = w * 4 + q;
      int col = j * 16 + (l >> 2);
      const char* src = (const char*)(w2pT + (size_t)(bc + col) * HIDD + kc * KCH + (l & 3) * 8);
      dma16(src, (char*)w2t[buf] + j * 1024);
    }
  };
  auto stage_f1 = [&](int j64, int buf) { // 8KB, 1 instr/wave; src pre-swizzled
    int col = w * 4 + (l >> 4);
    int kb  = ((l & 15) * 16) ^ ((col & 7) << 4);
    const char* src = (const char*)fc1wT + ((size_t)(j64 * KCH + col) * LATD) * 2 + kb;
    dma16(src, (char*)f1t[buf] + w * 1024);
  };

  // ---- G1: h rows w*16..+16, 32 cols of chunk j -> h_lds col-half (j&1)
  auto G1 = [&](int j) {
    const int buf = j & 1;
#pragma unroll
    for (int nt = 0; nt < 2; ++nt) {
      int col = nt * 16 + llo;
      f32x4 c1 = {};
#pragma unroll
      for (int ks = 0; ks < 4; ++ks) {
        int fb = col * 256 + ((ks * 64 + lhi * 16) ^ ((col & 7) << 4));
        bf16x8 b = *(const bf16x8*)((const char*)f1t[buf] + fb);
        c1 = __builtin_amdgcn_mfma_f32_16x16x32_bf16(za[ks], b, c1, 0, 0, 0);
      }
      float bias = fc1b[j * KCH + col];
#pragma unroll
      for (int r = 0; r < 4; ++r) {
        float pre = c1[r] + bias;
        float e   = __builtin_amdgcn_exp2f(pre * 2.88539008177792681f);  // e^(2x)
        float th  = 1.0f - 2.0f * __builtin_amdgcn_rcpf(e + 1.0f);
        int hr = w * 16 + lhi * 4 + r;
        int hb = (hr * 128 + (buf * KCH + col) * 2) ^ ((hr & 7) << 4);
        *(bf16_t*)((char*)h_lds + hb) = (bf16_t)th;
      }
    }
  };

  // ---- G2: wave tile 64 rows x 128 cols, K=32 (1 MFMA depth)
  auto G2 = [&](int kc) {
    const int buf = kc & 1;
    const int mrb = (w & 1) * 64;
    const int ncb = (w >> 1) * 128;
    bf16x8 a[4];
#pragma unroll
    for (int mt = 0; mt < 4; ++mt) {
      int hr = mrb + mt * 16 + llo;
      a[mt] = *(const bf16x8*)((const char*)h_lds +
               (hr * 128 + ((buf * 64 + lhi * 16) ^ ((hr & 7) << 4))));
    }
    __builtin_amdgcn_s_setprio(1);
#pragma unroll
    for (int nt = 0; nt < 8; ++nt) {
      int col = ncb + nt * 16 + llo;
      bf16x8 b = *(const bf16x8*)((const char*)w2t[buf] + (col * 64 + lhi * 16));
#pragma unroll
      for (int mt = 0; mt < 4; ++mt)
        acc[mt][nt] = __builtin_amdgcn_mfma_f32_16x16x32_bf16(a[mt], b, acc[mt][nt], 0, 0, 0);
    }
    __builtin_amdgcn_s_setprio(0);
  };

  // ---- pipeline
  stage_f1(0, 0);
  stage_w2(0);
  __syncthreads();             // f1t[0], w2t[0] ready
  stage_f1(1, 1);
  G1(0);
  __syncthreads();             // h half0, f1t[1] ready

  for (int kc = 0; kc < NKC; ++kc) {
    if (kc < NKC - 1) stage_w2(kc + 1);
    if (kc < NKC - 2) stage_f1(kc + 2, kc & 1);
    if (kc < NKC - 1) G1(kc + 1);
    G2(kc);
    if (kc < NKC - 1) __syncthreads();
  }

  // ---- epilogue: weight (nt even) and bias (nt odd) in the SAME lane; 64B stores
  {
    const int mrb = (w & 1) * 64;
    const int ncb = (w >> 1) * 128;
#pragma unroll
    for (int p = 0; p < 4; ++p) {
      int cw = bc + ncb + p * 32 + llo;          // collapsed weight col
      float bw = b2p[cw];
      float bb = b2p[cw + 16];
      int oc = (bc + ncb + p * 32) / 2 + llo;    // output col
#pragma unroll
      for (int mt = 0; mt < 4; ++mt) {
#pragma unroll
        for (int r = 0; r < 4; ++r) {
          int row = mrb + mt * 16 + lhi * 4 + r;
          float wv = acc[mt][2 * p][r] + bw;
          float bv = acc[mt][2 * p + 1][r] + bb;
          out[(b0 + row) * OC + oc] = inp_lds[row] * wv + bv;
        }
      }
    }
  }
}

extern "C" void kernel_launch(void* const* d_in, const int* in_sizes, int n_in,
                              void* d_out, int out_size, void* d_ws, size_t ws_size,
                              hipStream_t stream) {
  const float* x    = (const float*)d_in[0];
  const float* fc1w = (const float*)d_in[1];
  const float* fc1b = (const float*)d_in[2];
  const float* fc2w = (const float*)d_in[3];
  const float* fc2b = (const float*)d_in[4];
  const float* dil  = (const float*)d_in[5];
  const float* shp  = (const float*)d_in[6];
  float* out = (float*)d_out;

  // ws layout: fc1wT (512KB bf16) | w2pT (4MB bf16) | b2p (4KB f32)
  bf16_t* fc1wT = (bf16_t*)d_ws;
  bf16_t* w2pT  = fc1wT + (size_t)HIDD * LATD;
  float*  b2p   = (float*)(w2pT + (size_t)JC * HIDD);

  prep_fc1<<<(HIDD * LATD) / 256, 256, 0, stream>>>(fc1w, fc1wT);
  prep_fc2<<<(JC * HIDD) / 256, 256, 0, stream>>>(x, fc2w, fc2b, dil, shp, w2pT, b2p);
  wag_main<<<dim3(NB / BM, JC / BN), 512, 0, stream>>>(x, fc1b, fc1wT, w2pT, b2p, out);
}